// Round 6
// baseline (248.556 us; speedup 1.0000x reference)
//
#include <hip/hip_runtime.h>
#include <hip/hip_bf16.h>
#include <cstdint>
#include <cstddef>

#define TAU 1e-4f
#define LN_EPS 1e-5f

typedef unsigned short ushort_t;
typedef unsigned int uint_t;
typedef __attribute__((ext_vector_type(8))) short short8;
typedef __attribute__((ext_vector_type(4))) float f32x4;

__device__ __forceinline__ ushort_t f2bf(float f) {
    union { float f; unsigned int u; } c; c.f = f;
    unsigned int r = (c.u + 0x7fffu + ((c.u >> 16) & 1u)) >> 16;
    return (ushort_t)r;
}
__device__ __forceinline__ float bf2f(ushort_t u) {
    union { unsigned int u; float f; } c; c.u = ((unsigned int)u) << 16;
    return c.f;
}
__device__ __forceinline__ void glds16(const void* g, void* l) {
    __builtin_amdgcn_global_load_lds((const __attribute__((address_space(1))) unsigned int*)g,
                                     (__attribute__((address_space(3))) unsigned int*)l,
                                     16, 0, 0);
}

// ---------------------------------------------------------------------------
// kA: merged weight-prep + per-b LN1/graph kernel. grid 1542:
//   blockIdx < 1024 : LN1G path (b = blockIdx)
//   else            : prep path (id = blockIdx - 1024, 0..517)
// ---------------------------------------------------------------------------
__global__ __launch_bounds__(256) void kA(
    const float* __restrict__ xg, const float* __restrict__ maskg,
    const float* __restrict__ Wg, const float* __restrict__ bg,
    const float* __restrict__ ls, const float* __restrict__ g1,
    const float* __restrict__ b1, ushort_t* __restrict__ xnbuf,
    float* __restrict__ Mbuf, float* __restrict__ gbuf,
    const float* __restrict__ Wv, const float* __restrict__ We,
    const float* __restrict__ Wo, const float* __restrict__ bv,
    const float* __restrict__ be, const float* __restrict__ Wf1,
    const float* __restrict__ Wf2, ushort_t* __restrict__ WkT,
    ushort_t* __restrict__ Wf1T, ushort_t* __restrict__ Wf2T,
    float* __restrict__ cvpart, float* __restrict__ beWo) {
    __shared__ __align__(16) float POOL[8880];
    const int tid = threadIdx.x;

    if (blockIdx.x >= 1024) {
        const int id = blockIdx.x - 1024;
        if (id < 384) {
            float (*rowS)[256] = (float(*)[256])POOL;
            const int q0 = (id & 63) * 4;
            const int w = id >> 6;
            const int half = w / 3, s = w - half * 3;
            const float* src = half ? We : Wv;
#pragma unroll
            for (int r = 0; r < 4; ++r)
                rowS[r][tid] = src[(size_t)(q0 + r) * 768 + s * 256 + tid];
            __syncthreads();
            const float* wo = Wo + (size_t)(half * 768 + s * 256) * 256 + tid;
            float a0 = 0.f, a1 = 0.f, a2 = 0.f, a3 = 0.f;
            for (int d = 0; d < 256; ++d) {
                float wv = wo[(size_t)d * 256];
                a0 += rowS[0][d] * wv; a1 += rowS[1][d] * wv;
                a2 += rowS[2][d] * wv; a3 += rowS[3][d] * wv;
            }
            const int rt = half * 3 + s;
            ushort4 pk;
            pk.x = f2bf(a0); pk.y = f2bf(a1); pk.z = f2bf(a2); pk.w = f2bf(a3);
            *(ushort4*)&WkT[(size_t)(rt * 256 + tid) * 256 + q0] = pk;
        } else if (id < 390) {
            const int w = id - 384;
            const int half = w / 3, s = w - half * 3;
            const float* vec = half ? be : bv;
            POOL[tid] = vec[s * 256 + tid];
            __syncthreads();
            const float* wo = Wo + (size_t)(half * 768 + s * 256) * 256 + tid;
            float acc = 0.f;
            for (int d = 0; d < 256; ++d) acc += POOL[d] * wo[(size_t)d * 256];
            if (half) beWo[s * 256 + tid] = acc;
            else cvpart[s * 256 + tid] = acc;
        } else {
            float (*tS)[65] = (float(*)[65])POOL;
            const float* src; ushort_t* dst;
            int sr0, sc0, ss, dr0, dc0, ds_;
            if (id < 454) {
                int t = id - 390; int ki = t & 3, ni = t >> 2;
                src = Wf1; ss = 1024; sr0 = ki * 64; sc0 = ni * 64;
                dst = Wf1T; ds_ = 256; dr0 = ni * 64; dc0 = ki * 64;
            } else {
                int t = id - 454; int ki = t >> 2, ni = t & 3;
                src = Wf2; ss = 256; sr0 = ki * 64; sc0 = ni * 64;
                dst = Wf2T; ds_ = 1024; dr0 = ni * 64; dc0 = ki * 64;
            }
            const int rl = tid >> 6, cl = tid & 63;
#pragma unroll
            for (int p = 0; p < 16; ++p) {
                int r = p * 4 + rl;
                tS[r][cl] = src[(size_t)(sr0 + r) * ss + sc0 + cl];
            }
            __syncthreads();
#pragma unroll
            for (int p = 0; p < 16; ++p) {
                int r = p * 4 + rl;
                dst[(size_t)(dr0 + r) * ds_ + dc0 + cl] = f2bf(tS[cl][r]);
            }
        }
        return;
    }

    // ---- LN1G path ----
    const int b = blockIdx.x;
    float (*XS)[260] = (float(*)[260])POOL;          // 4160 floats
    float* WB = POOL + 4160;                         // 4160 floats
    float (*Pl)[17] = (float(*)[17])(POOL + 8320);   // 272
    float (*dotm)[17] = (float(*)[17])(POOL + 8592); // 272
    float* mk = POOL + 8864;                         // 16
    float (*WgT)[260] = (float(*)[260])WB;
    float (*DsqS)[17] = (float(*)[17])WB;
    float (*Wh)[16][17] = (float(*)[16][17])(WB + 272);
    float* Ts = WB + 1088;

    const float* xb = xg + (size_t)b * 4096;
#pragma unroll
    for (int i = 0; i < 4; ++i) {
        int idx = tid * 4 + i * 1024;
        int k = idx >> 8, c = idx & 255;
        float4 v = *(const float4*)&xb[idx];
        XS[k][c] = v.x; XS[k][c + 1] = v.y; XS[k][c + 2] = v.z; XS[k][c + 3] = v.w;
    }
    {
        const float4* wgp = (const float4*)(Wg + tid * 16);
        float4 w0 = wgp[0], w1 = wgp[1], w2 = wgp[2], w3 = wgp[3];
        WgT[0][tid] = w0.x; WgT[1][tid] = w0.y; WgT[2][tid] = w0.z; WgT[3][tid] = w0.w;
        WgT[4][tid] = w1.x; WgT[5][tid] = w1.y; WgT[6][tid] = w1.z; WgT[7][tid] = w1.w;
        WgT[8][tid] = w2.x; WgT[9][tid] = w2.y; WgT[10][tid] = w2.z; WgT[11][tid] = w2.w;
        WgT[12][tid] = w3.x; WgT[13][tid] = w3.y; WgT[14][tid] = w3.z; WgT[15][tid] = w3.w;
    }
    if (tid < 16) mk[tid] = maskg[b * 16 + tid];
    __syncthreads();

    // LN1
    {
        const int k = tid >> 4, c = tid & 15;
        float s = 0.f;
#pragma unroll
        for (int j = 0; j < 16; ++j) s += XS[k][c + 16 * j];
        for (int off = 8; off; off >>= 1) s += __shfl_down(s, off, 16);
        float mean = __shfl(s, 0, 16) * (1.f / 256.f);
        float vs = 0.f;
#pragma unroll
        for (int j = 0; j < 16; ++j) { float d = XS[k][c + 16 * j] - mean; vs += d * d; }
        for (int off = 8; off; off >>= 1) vs += __shfl_down(vs, off, 16);
        float rstd = rsqrtf(__shfl(vs, 0, 16) * (1.f / 256.f) + LN_EPS);
#pragma unroll
        for (int j = 0; j < 16; ++j) {
            int cc = c + 16 * j;
            XS[k][cc] = (XS[k][cc] - mean) * rstd * g1[cc] + b1[cc];
        }
    }
    __syncthreads();

    // xn (bf16, packed pairs)
#pragma unroll
    for (int i = 0; i < 8; ++i) {
        int idx2 = tid * 2 + i * 512;
        int k = idx2 >> 8, c = idx2 & 255;
        uint_t v = (uint_t)f2bf(XS[k][c]) | ((uint_t)f2bf(XS[k][c + 1]) << 16);
        *(uint_t*)&xnbuf[(size_t)b * 4096 + idx2] = v;
    }

    // P[k][c]
    {
        const int k = tid >> 4, c = tid & 15;
        float acc = bg[c];
#pragma unroll
        for (int q4 = 0; q4 < 64; ++q4) {
            float4 wv = *(const float4*)&WgT[c][q4 * 4];
            float4 xv = *(const float4*)&XS[k][q4 * 4];
            acc += wv.x * xv.x + wv.y * xv.y + wv.z * xv.z + wv.w * xv.w;
        }
        Pl[k][c] = acc;
    }
    __syncthreads();   // WgT dead from here; WB reused
    const int k = tid >> 4, m = tid & 15;
    {
        float d = 0.f;
#pragma unroll
        for (int c = 0; c < 16; ++c) d += Pl[k][c] * Pl[m][c];
        dotm[k][m] = d;
    }
    __syncthreads();
    {
        float v = dotm[k][k] + dotm[m][m] - 2.f * dotm[k][m];
        DsqS[k][m] = fmaxf(v, 0.f) * mk[k] * mk[m];
    }
    {
        float d = DsqS[k][m];
        float mm = mk[k] * mk[m];
#pragma unroll
        for (int s = 0; s < 3; ++s) {
            float i2 = 1.f / (2.f * expf(2.f * ls[s]) + 1e-8f);
            Wh[s][k][m] = (k == m) ? 0.f : expf(-d * i2) * mm;
        }
    }
    __syncthreads();
    if (tid < 48) {
        int s = tid >> 4, j = tid & 15;
        float t = 0.f;
        for (int i = 0; i < j; ++i) {
            float d = 0.f;
            for (int jj = j + 1; jj < 16; ++jj) d += Wh[s][j][jj] * Wh[s][i][jj];
            t += Wh[s][i][j] * d;
        }
        Ts[s * 16 + j] = t;
    }
    __syncthreads();
    float gd = 0.f;
#pragma unroll
    for (int o = 0; o < 16; ++o) {
        if (o == m) continue;
        int u = o < m ? o : m, v = o < m ? m : o;
        float gu = (u == k) ? (float)(2 * k - 15) : ((u > k) ? 1.f : -1.f);
        float gv = (v == k) ? (float)(2 * k - 15) : ((v > k) ? 1.f : -1.f);
        gd += -gu * mk[u] + gv * mk[v];
        if (u == k || v == k) gd += TAU;
    }
    float* mb = Mbuf + (size_t)b * 1536;
#pragma unroll
    for (int s = 0; s < 3; ++s) {
        float rs = 0.f;
#pragma unroll
        for (int o = 0; o < 16; ++o) rs += Wh[s][k][o];
        float l0 = (k == m) ? (rs + TAU) : -Wh[s][k][m];
        float G = gd + ((k == m) ? 4.f * Ts[s * 16 + k] : 0.f);
        mb[s * 256 + tid] = l0;
        mb[768 + s * 256 + tid] = G;
        float gg = G;
        for (int off = 8; off; off >>= 1) gg += __shfl_down(gg, off, 16);
        if (m == 0) gbuf[b * 48 + k * 3 + s] = 0.5f * gg;
    }
}

// ---------------------------------------------------------------------------
// gemm128 core (unchanged)
// ---------------------------------------------------------------------------
__device__ __forceinline__ void gemm128(const ushort_t* __restrict__ A,
                                        const ushort_t* __restrict__ Bt,
                                        int Kdim, int m0, int n0,
                                        f32x4 acc[4][4],
                                        ushort_t (*As)[32], ushort_t (*Bs)[32]) {
    const int tid = threadIdx.x;
    const int wave = tid >> 6, lane = tid & 63;
    const int lq = lane >> 4, lr = lane & 15;
    const int wm = wave >> 1, wn = wave & 1;
    const int r = tid >> 2, ca = (tid & 3) << 3;
    const ushort_t* Ag0 = A + (size_t)(m0 + r) * Kdim + ca;
    const ushort_t* Ag1 = A + (size_t)(m0 + 64 + r) * Kdim + ca;
    const ushort_t* Bg0 = Bt + (size_t)(n0 + r) * Kdim + ca;
    const ushort_t* Bg1 = Bt + (size_t)(n0 + 64 + r) * Kdim + ca;
    char* AsD0 = (char*)As + wave * 1024;
    char* AsD1 = (char*)As + 4096 + wave * 1024;
    char* BsD0 = (char*)Bs + wave * 1024;
    char* BsD1 = (char*)Bs + 4096 + wave * 1024;
    for (int kt = 0; kt < Kdim; kt += 32) {
        __syncthreads();
        glds16(Ag0 + kt, AsD0);
        glds16(Ag1 + kt, AsD1);
        glds16(Bg0 + kt, BsD0);
        glds16(Bg1 + kt, BsD1);
        __syncthreads();
        short8 af[4], bfr[4];
#pragma unroll
        for (int i = 0; i < 4; ++i) af[i] = *(const short8*)&As[wm * 64 + i * 16 + lr][lq * 8];
#pragma unroll
        for (int j = 0; j < 4; ++j) bfr[j] = *(const short8*)&Bs[wn * 64 + j * 16 + lr][lq * 8];
#pragma unroll
        for (int i = 0; i < 4; ++i)
#pragma unroll
            for (int j = 0; j < 4; ++j)
                acc[i][j] = __builtin_amdgcn_mfma_f32_16x16x32_bf16(af[i], bfr[j], acc[i][j], 0, 0, 0);
    }
}

// kY: Y = xn @ Wk' (M=16384, N=1536, K=256), 128x128 tiles, grid (128,12)
__global__ __launch_bounds__(256) void kY_gemm(const ushort_t* __restrict__ xn,
                                               const ushort_t* __restrict__ WkT,
                                               ushort_t* __restrict__ Y) {
    __shared__ ushort_t As[128][32];
    __shared__ ushort_t Bs[128][32];
    const int tid = threadIdx.x;
    const int m0 = blockIdx.x * 128, n0 = blockIdx.y * 128;
    f32x4 acc[4][4] = {};
    gemm128(xn, WkT, 256, m0, n0, acc, As, Bs);
    const int wave = tid >> 6, lane = tid & 63, lq = lane >> 4, lr = lane & 15;
    const int wm = wave >> 1, wn = wave & 1;
#pragma unroll
    for (int i = 0; i < 4; ++i)
#pragma unroll
        for (int j = 0; j < 4; ++j) {
            int n = n0 + wn * 64 + j * 16 + lr;
#pragma unroll
            for (int v = 0; v < 4; ++v) {
                int rg = m0 + wm * 64 + i * 16 + lq * 4 + v;
                Y[(size_t)rg * 1536 + n] = f2bf(acc[i][j][v]);
            }
        }
}

// kZ: per-b Z = sum_rt M_rt @ Y_rt; epilogue x' = x + Z + cv + sum g*beWo
__global__ __launch_bounds__(256) void kZ_apply(
    const ushort_t* __restrict__ Y, const float* __restrict__ Mbuf,
    const float* __restrict__ xin, const float* __restrict__ bo,
    const float* __restrict__ cvpart, const float* __restrict__ beWo,
    const float* __restrict__ gbuf, float* __restrict__ xp) {
    __shared__ __align__(16) char YsRaw[49152];
    ushort_t* Ys = (ushort_t*)YsRaw;
    __shared__ float Ms[1536];
    __shared__ float gS[48];
    const int b = blockIdx.x, tid = threadIdx.x;
    const int wave = tid >> 6, lane = tid & 63;
    const char* Ybc = (const char*)(Y + (size_t)b * 24576);
#pragma unroll
    for (int it = 0; it < 12; ++it) {
        int base = it * 4096 + wave * 1024;
        glds16(Ybc + base + lane * 16, YsRaw + base);
    }
#pragma unroll
    for (int i = 0; i < 6; ++i) Ms[tid + i * 256] = Mbuf[(size_t)b * 1536 + tid + i * 256];
    if (tid < 48) gS[tid] = gbuf[b * 48 + tid];
    __syncthreads();

    const int q = tid;
    float yv[96];
#pragma unroll
    for (int rt = 0; rt < 6; ++rt)
#pragma unroll
        for (int l = 0; l < 16; ++l)
            yv[rt * 16 + l] = bf2f(Ys[l * 1536 + rt * 256 + q]);

    float accv[16];
#pragma unroll
    for (int k = 0; k < 16; ++k) {
        float a = 0.f;
#pragma unroll
        for (int rt = 0; rt < 6; ++rt) {
            const float4* mp = (const float4*)&Ms[rt * 256 + k * 16];
            float4 m0 = mp[0], m1 = mp[1], m2 = mp[2], m3 = mp[3];
            const float* yp = &yv[rt * 16];
            a += m0.x * yp[0] + m0.y * yp[1] + m0.z * yp[2] + m0.w * yp[3]
               + m1.x * yp[4] + m1.y * yp[5] + m1.z * yp[6] + m1.w * yp[7]
               + m2.x * yp[8] + m2.y * yp[9] + m2.z * yp[10] + m2.w * yp[11]
               + m3.x * yp[12] + m3.y * yp[13] + m3.z * yp[14] + m3.w * yp[15];
        }
        accv[k] = a;
    }

    float cv = bo[q] + TAU * (cvpart[q] + cvpart[256 + q] + cvpart[512 + q]);
    float bw0 = beWo[q], bw1 = beWo[256 + q], bw2 = beWo[512 + q];
    const float* xb2 = xin + (size_t)b * 4096;
    float* xpb = xp + (size_t)b * 4096;
#pragma unroll
    for (int k = 0; k < 16; ++k) {
        xpb[k * 256 + q] = accv[k] + xb2[k * 256 + q] + cv +
                           gS[k * 3] * bw0 + gS[k * 3 + 1] * bw1 + gS[k * 3 + 2] * bw2;
    }
}

// ---------------------------------------------------------------------------
// kFFN: fused LN2 + gelu(h@Wf1+bf1)@Wf2 + bf2 + xp residual. grid 256,
// 64-row tiles. h and F1 never touch HBM.
// ---------------------------------------------------------------------------
__global__ __launch_bounds__(256) void kFFN(
    const float* __restrict__ xp, const ushort_t* __restrict__ Wf1T,
    const float* __restrict__ bf1, const ushort_t* __restrict__ Wf2T,
    const float* __restrict__ bf2, const float* __restrict__ g2,
    const float* __restrict__ b2, float* __restrict__ out) {
    __shared__ ushort_t hS[8][64][34];    // LN2 output, kt-chunked (A for F1 GEMM)
    __shared__ ushort_t F1S[4][64][34];   // gelu chunk (A for out GEMM)
    __shared__ ushort_t Bs1[128][32];
    __shared__ ushort_t Bs2[256][32];
    __shared__ float g2S[256], b2S[256], bf2S[256], bf1S[1024];
    const int tid = threadIdx.x;
    const int wave = tid >> 6, lane = tid & 63;
    const int lq = lane >> 4, lr = lane & 15;
    const int m0 = blockIdx.x * 64;

    g2S[tid] = g2[tid]; b2S[tid] = b2[tid]; bf2S[tid] = bf2[tid];
#pragma unroll
    for (int i = 0; i < 4; ++i) bf1S[tid + i * 256] = bf1[tid + i * 256];

    // ---- LN2 prologue: row r = tid>>2, col-quarter c4 = tid&3 ----
    {
        const int r = tid >> 2, c4 = tid & 3;
        const float* xr = xp + (size_t)(m0 + r) * 256 + c4 * 64;
        float vals[64];
        float s = 0.f;
#pragma unroll
        for (int i = 0; i < 16; ++i) {
            float4 v = *(const float4*)(xr + i * 4);
            vals[i * 4 + 0] = v.x; vals[i * 4 + 1] = v.y;
            vals[i * 4 + 2] = v.z; vals[i * 4 + 3] = v.w;
            s += (v.x + v.y) + (v.z + v.w);
        }
        s += __shfl_xor(s, 1, 64); s += __shfl_xor(s, 2, 64);
        float mean = s * (1.f / 256.f);
        float q = 0.f;
#pragma unroll
        for (int i = 0; i < 64; ++i) { float d = vals[i] - mean; q += d * d; }
        q += __shfl_xor(q, 1, 64); q += __shfl_xor(q, 2, 64);
        float rstd = rsqrtf(q * (1.f / 256.f) + LN_EPS);
        __syncthreads();   // g2S/b2S ready
#pragma unroll
        for (int i = 0; i < 32; ++i) {
            int col = c4 * 64 + i * 2;
            float h0 = (vals[i * 2] - mean) * rstd * g2S[col] + b2S[col];
            float h1 = (vals[i * 2 + 1] - mean) * rstd * g2S[col + 1] + b2S[col + 1];
            uint_t pk = (uint_t)f2bf(h0) | ((uint_t)f2bf(h1) << 16);
            *(uint_t*)&hS[col >> 5][r][col & 31] = pk;
        }
    }
    __syncthreads();

    const int wm2 = wave >> 1, wn2 = wave & 1;
    const int rS = tid >> 2, caS = (tid & 3) << 3;
    f32x4 acc2[4][4] = {};
    for (int nc = 0; nc < 8; ++nc) {
        // F1 chunk: gelu(h @ Wf1[:, nc*128..+128) + b)
        f32x4 acc1[2][4] = {};
        const ushort_t* Bg0 = Wf1T + (size_t)(nc * 128 + rS) * 256 + caS;
        const ushort_t* Bg1 = Wf1T + (size_t)(nc * 128 + 64 + rS) * 256 + caS;
        for (int kt = 0; kt < 256; kt += 32) {
            __syncthreads();
            glds16(Bg0 + kt, (char*)Bs1 + wave * 1024);
            glds16(Bg1 + kt, (char*)Bs1 + 4096 + wave * 1024);
            __syncthreads();
            const int kti = kt >> 5;
            short8 af[2], bfv[4];
#pragma unroll
            for (int i = 0; i < 2; ++i)
                af[i] = *(const short8*)&hS[kti][wm2 * 32 + i * 16 + lr][lq * 8];
#pragma unroll
            for (int j = 0; j < 4; ++j)
                bfv[j] = *(const short8*)&Bs1[wn2 * 64 + j * 16 + lr][lq * 8];
#pragma unroll
            for (int i = 0; i < 2; ++i)
#pragma unroll
                for (int j = 0; j < 4; ++j)
                    acc1[i][j] = __builtin_amdgcn_mfma_f32_16x16x32_bf16(af[i], bfv[j], acc1[i][j], 0, 0, 0);
        }
        __syncthreads();
        // gelu -> F1S
#pragma unroll
        for (int i = 0; i < 2; ++i)
#pragma unroll
            for (int j = 0; j < 4; ++j) {
                int colc = wn2 * 64 + j * 16 + lr;
                float bn = bf1S[nc * 128 + colc];
#pragma unroll
                for (int v = 0; v < 4; ++v) {
                    int row = wm2 * 32 + i * 16 + lq * 4 + v;
                    float u = acc1[i][j][v] + bn;
                    float gl = 0.5f * u * (1.f + erff(u * 0.70710678118f));
                    F1S[colc >> 5][row][colc & 31] = f2bf(gl);
                }
            }
        __syncthreads();
        // out += F1chunk @ Wf2[nc*128..+128, :]
        for (int kt2 = 0; kt2 < 4; ++kt2) {
            __syncthreads();
            const ushort_t* Bg = Wf2T + (size_t)rS * 1024 + nc * 128 + kt2 * 32 + caS;
#pragma unroll
            for (int c = 0; c < 4; ++c)
                glds16(Bg + (size_t)c * 64 * 1024, (char*)Bs2 + c * 4096 + wave * 1024);
            __syncthreads();
            short8 af2[4], bfv2[4];
#pragma unroll
            for (int i = 0; i < 4; ++i)
                af2[i] = *(const short8*)&F1S[kt2][i * 16 + lr][lq * 8];
#pragma unroll
            for (int j = 0; j < 4; ++j)
                bfv2[j] = *(const short8*)&Bs2[wave * 64 + j * 16 + lr][lq * 8];
#pragma unroll
            for (int i = 0; i < 4; ++i)
#pragma unroll
                for (int j = 0; j < 4; ++j)
                    acc2[i][j] = __builtin_amdgcn_mfma_f32_16x16x32_bf16(af2[i], bfv2[j], acc2[i][j], 0, 0, 0);
        }
    }
    // epilogue: out = xp + acc2 + bf2
#pragma unroll
    for (int i = 0; i < 4; ++i)
#pragma unroll
        for (int j = 0; j < 4; ++j) {
            int n = wave * 64 + j * 16 + lr;
            float bn = bf2S[n];
#pragma unroll
            for (int v = 0; v < 4; ++v) {
                size_t idx = (size_t)(m0 + i * 16 + lq * 4 + v) * 256 + n;
                out[idx] = xp[idx] + acc2[i][j][v] + bn;
            }
        }
}

extern "C" void kernel_launch(void* const* d_in, const int* in_sizes, int n_in,
                              void* d_out, int out_size, void* d_ws, size_t ws_size,
                              hipStream_t stream) {
    const float* x = (const float*)d_in[0];
    const float* mask = (const float*)d_in[1];
    const float* Wg = (const float*)d_in[2];
    const float* bg = (const float*)d_in[3];
    const float* ls = (const float*)d_in[4];
    const float* Wv = (const float*)d_in[5];
    const float* bv = (const float*)d_in[6];
    const float* We = (const float*)d_in[7];
    const float* be = (const float*)d_in[8];
    const float* Wo = (const float*)d_in[9];
    const float* bo = (const float*)d_in[10];
    const float* g1 = (const float*)d_in[11];
    const float* b1 = (const float*)d_in[12];
    const float* g2 = (const float*)d_in[13];
    const float* b2 = (const float*)d_in[14];
    const float* Wf1 = (const float*)d_in[15];
    const float* bf1 = (const float*)d_in[16];
    const float* Wf2 = (const float*)d_in[17];
    const float* bf2 = (const float*)d_in[18];
    float* out = (float*)d_out;

    char* ws = (char*)d_ws;
    ushort_t* Y = (ushort_t*)(ws);                      // 50,331,648
    ushort_t* WkT = (ushort_t*)(ws + 50331648);         //    786,432
    ushort_t* Wf1T = (ushort_t*)(ws + 51118080);        //    524,288
    ushort_t* Wf2T = (ushort_t*)(ws + 51642368);        //    524,288
    float* cvpart = (float*)(ws + 52166656);            //      3,072
    float* beWo = (float*)(ws + 52169728);              //      3,072
    float* gbuf = (float*)(ws + 52172800);              //    196,608
    float* xp = (float*)(ws + 52369408);                // 16,777,216
    ushort_t* xnbuf = (ushort_t*)(ws + 77535232);       //  8,388,608
    float* Mbuf = (float*)(ws + 85923840);              //  6,291,456  -> end 92,215,296

    kA<<<dim3(1542), dim3(256), 0, stream>>>(x, mask, Wg, bg, ls, g1, b1,
                                             xnbuf, Mbuf, gbuf,
                                             Wv, We, Wo, bv, be, Wf1, Wf2,
                                             WkT, Wf1T, Wf2T, cvpart, beWo);
    kY_gemm<<<dim3(128, 12), dim3(256), 0, stream>>>(xnbuf, WkT, Y);
    kZ_apply<<<dim3(1024), dim3(256), 0, stream>>>(Y, Mbuf, x, bo, cvpart, beWo, gbuf, xp);
    kFFN<<<dim3(256), dim3(256), 0, stream>>>(xp, Wf1T, bf1, Wf2T, bf2, g2, b2, out);
}

// Round 7
// 221.323 us; speedup vs baseline: 1.1230x; 1.1230x over previous
//
#include <hip/hip_runtime.h>
#include <hip/hip_bf16.h>
#include <cstdint>
#include <cstddef>

#define TAU 1e-4f
#define LN_EPS 1e-5f

typedef unsigned short ushort_t;
typedef unsigned int uint_t;
typedef __attribute__((ext_vector_type(8))) short short8;
typedef __attribute__((ext_vector_type(4))) float f32x4;

__device__ __forceinline__ ushort_t f2bf(float f) {
    union { float f; unsigned int u; } c; c.f = f;
    unsigned int r = (c.u + 0x7fffu + ((c.u >> 16) & 1u)) >> 16;
    return (ushort_t)r;
}
__device__ __forceinline__ void glds16(const void* g, void* l) {
    __builtin_amdgcn_global_load_lds((const __attribute__((address_space(1))) unsigned int*)g,
                                     (__attribute__((address_space(3))) unsigned int*)l,
                                     16, 0, 0);
}

// ---------------------------------------------------------------------------
// kA: merged weight-prep + per-b LN1/graph/Mcat kernel. grid 1542:
//   blockIdx < 1024 : per-b path (LN1, P, Dsq, graph algebra, Mcat rows)
//   else            : prep path (id = blockIdx - 1024, 0..517)
// Mcat[(b*16+k)*1536 + rt*256 + q] = sum_l M_rt[k][l] * xn[b][l][q]  (bf16)
// where M_rt = L0_s (rt<3) or G_s (rt>=3).
// ---------------------------------------------------------------------------
__global__ __launch_bounds__(256) void kA(
    const float* __restrict__ xg, const float* __restrict__ maskg,
    const float* __restrict__ Wg, const float* __restrict__ bg,
    const float* __restrict__ ls, const float* __restrict__ g1,
    const float* __restrict__ b1, ushort_t* __restrict__ Mcat,
    float* __restrict__ gbuf,
    const float* __restrict__ Wv, const float* __restrict__ We,
    const float* __restrict__ Wo, const float* __restrict__ bv,
    const float* __restrict__ be, const float* __restrict__ Wf1,
    const float* __restrict__ Wf2, ushort_t* __restrict__ WcatT,
    ushort_t* __restrict__ Wf1T, ushort_t* __restrict__ Wf2T,
    float* __restrict__ cvpart, float* __restrict__ beWo) {
    __shared__ __align__(16) float POOL[9872];
    const int tid = threadIdx.x;

    if (blockIdx.x >= 1024) {
        const int id = blockIdx.x - 1024;
        if (id < 384) {
            float (*rowS)[256] = (float(*)[256])POOL;
            const int q0 = (id & 63) * 4;
            const int w = id >> 6;
            const int half = w / 3, s = w - half * 3;
            const float* src = half ? We : Wv;
#pragma unroll
            for (int r = 0; r < 4; ++r)
                rowS[r][tid] = src[(size_t)(q0 + r) * 768 + s * 256 + tid];
            __syncthreads();
            const float* wo = Wo + (size_t)(half * 768 + s * 256) * 256 + tid;
            float a0 = 0.f, a1 = 0.f, a2 = 0.f, a3 = 0.f;
            for (int d = 0; d < 256; ++d) {
                float wv = wo[(size_t)d * 256];
                a0 += rowS[0][d] * wv; a1 += rowS[1][d] * wv;
                a2 += rowS[2][d] * wv; a3 += rowS[3][d] * wv;
            }
            const int rt = half * 3 + s;
            ushort4 pk;
            pk.x = f2bf(a0); pk.y = f2bf(a1); pk.z = f2bf(a2); pk.w = f2bf(a3);
            // WcatT[n][rt*256+q] = W_rt[q][n]  (B^T for the kZY gemm, K=1536)
            *(ushort4*)&WcatT[(size_t)tid * 1536 + rt * 256 + q0] = pk;
        } else if (id < 390) {
            const int w = id - 384;
            const int half = w / 3, s = w - half * 3;
            const float* vec = half ? be : bv;
            POOL[tid] = vec[s * 256 + tid];
            __syncthreads();
            const float* wo = Wo + (size_t)(half * 768 + s * 256) * 256 + tid;
            float acc = 0.f;
            for (int d = 0; d < 256; ++d) acc += POOL[d] * wo[(size_t)d * 256];
            if (half) beWo[s * 256 + tid] = acc;
            else cvpart[s * 256 + tid] = acc;
        } else {
            float (*tS)[65] = (float(*)[65])POOL;
            const float* src; ushort_t* dst;
            int sr0, sc0, ss, dr0, dc0, ds_;
            if (id < 454) {
                int t = id - 390; int ki = t & 3, ni = t >> 2;
                src = Wf1; ss = 1024; sr0 = ki * 64; sc0 = ni * 64;
                dst = Wf1T; ds_ = 256; dr0 = ni * 64; dc0 = ki * 64;
            } else {
                int t = id - 454; int ki = t >> 2, ni = t & 3;
                src = Wf2; ss = 256; sr0 = ki * 64; sc0 = ni * 64;
                dst = Wf2T; ds_ = 1024; dr0 = ni * 64; dc0 = ki * 64;
            }
            const int rl = tid >> 6, cl = tid & 63;
#pragma unroll
            for (int p = 0; p < 16; ++p) {
                int r = p * 4 + rl;
                tS[r][cl] = src[(size_t)(sr0 + r) * ss + sc0 + cl];
            }
            __syncthreads();
#pragma unroll
            for (int p = 0; p < 16; ++p) {
                int r = p * 4 + rl;
                dst[(size_t)(dr0 + r) * ds_ + dc0 + cl] = f2bf(tS[cl][r]);
            }
        }
        return;
    }

    // ---- per-b path ----
    const int b = blockIdx.x;
    float (*XS)[260] = (float(*)[260])POOL;          // 0..4160  (xn, live to end)
    float* WB = POOL + 4160;                         // 4160..8320
    float (*Pl)[17] = (float(*)[17])(POOL + 8320);   // dead before Ms
    float (*dotm)[17] = (float(*)[17])(POOL + 8592); // dead before Ms
    float* Ms = POOL + 8320;                         // 8320..9856  [6][256]
    float* mk = POOL + 9856;                         // 16
    float (*WgT)[260] = (float(*)[260])WB;
    float (*DsqS)[17] = (float(*)[17])WB;
    float (*Wh)[16][17] = (float(*)[16][17])(WB + 272);
    float* Ts = WB + 1088;

    const float* xb = xg + (size_t)b * 4096;
#pragma unroll
    for (int i = 0; i < 4; ++i) {
        int idx = tid * 4 + i * 1024;
        int k = idx >> 8, c = idx & 255;
        float4 v = *(const float4*)&xb[idx];
        XS[k][c] = v.x; XS[k][c + 1] = v.y; XS[k][c + 2] = v.z; XS[k][c + 3] = v.w;
    }
    {
        const float4* wgp = (const float4*)(Wg + tid * 16);
        float4 w0 = wgp[0], w1 = wgp[1], w2 = wgp[2], w3 = wgp[3];
        WgT[0][tid] = w0.x; WgT[1][tid] = w0.y; WgT[2][tid] = w0.z; WgT[3][tid] = w0.w;
        WgT[4][tid] = w1.x; WgT[5][tid] = w1.y; WgT[6][tid] = w1.z; WgT[7][tid] = w1.w;
        WgT[8][tid] = w2.x; WgT[9][tid] = w2.y; WgT[10][tid] = w2.z; WgT[11][tid] = w2.w;
        WgT[12][tid] = w3.x; WgT[13][tid] = w3.y; WgT[14][tid] = w3.z; WgT[15][tid] = w3.w;
    }
    if (tid < 16) mk[tid] = maskg[b * 16 + tid];
    __syncthreads();

    // LN1
    {
        const int k = tid >> 4, c = tid & 15;
        float s = 0.f;
#pragma unroll
        for (int j = 0; j < 16; ++j) s += XS[k][c + 16 * j];
        for (int off = 8; off; off >>= 1) s += __shfl_down(s, off, 16);
        float mean = __shfl(s, 0, 16) * (1.f / 256.f);
        float vs = 0.f;
#pragma unroll
        for (int j = 0; j < 16; ++j) { float d = XS[k][c + 16 * j] - mean; vs += d * d; }
        for (int off = 8; off; off >>= 1) vs += __shfl_down(vs, off, 16);
        float rstd = rsqrtf(__shfl(vs, 0, 16) * (1.f / 256.f) + LN_EPS);
#pragma unroll
        for (int j = 0; j < 16; ++j) {
            int cc = c + 16 * j;
            XS[k][cc] = (XS[k][cc] - mean) * rstd * g1[cc] + b1[cc];
        }
    }
    __syncthreads();

    // P[k][c]
    {
        const int k = tid >> 4, c = tid & 15;
        float acc = bg[c];
#pragma unroll
        for (int q4 = 0; q4 < 64; ++q4) {
            float4 wv = *(const float4*)&WgT[c][q4 * 4];
            float4 xv = *(const float4*)&XS[k][q4 * 4];
            acc += wv.x * xv.x + wv.y * xv.y + wv.z * xv.z + wv.w * xv.w;
        }
        Pl[k][c] = acc;
    }
    __syncthreads();   // WgT dead; WB reused
    const int k = tid >> 4, m = tid & 15;
    {
        float d = 0.f;
#pragma unroll
        for (int c = 0; c < 16; ++c) d += Pl[k][c] * Pl[m][c];
        dotm[k][m] = d;
    }
    __syncthreads();
    {
        float v = dotm[k][k] + dotm[m][m] - 2.f * dotm[k][m];
        DsqS[k][m] = fmaxf(v, 0.f) * mk[k] * mk[m];
    }
    {
        float d = DsqS[k][m];
        float mm = mk[k] * mk[m];
#pragma unroll
        for (int s = 0; s < 3; ++s) {
            float i2 = 1.f / (2.f * expf(2.f * ls[s]) + 1e-8f);
            Wh[s][k][m] = (k == m) ? 0.f : expf(-d * i2) * mm;
        }
    }
    __syncthreads();   // Pl/dotm dead from here (Ms region)
    if (tid < 48) {
        int s = tid >> 4, j = tid & 15;
        float t = 0.f;
        for (int i = 0; i < j; ++i) {
            float d = 0.f;
            for (int jj = j + 1; jj < 16; ++jj) d += Wh[s][j][jj] * Wh[s][i][jj];
            t += Wh[s][i][j] * d;
        }
        Ts[s * 16 + j] = t;
    }
    __syncthreads();
    // G_down closed form (s-independent)
    float gd = 0.f;
#pragma unroll
    for (int o = 0; o < 16; ++o) {
        if (o == m) continue;
        int u = o < m ? o : m, v = o < m ? m : o;
        float gu = (u == k) ? (float)(2 * k - 15) : ((u > k) ? 1.f : -1.f);
        float gv = (v == k) ? (float)(2 * k - 15) : ((v > k) ? 1.f : -1.f);
        gd += -gu * mk[u] + gv * mk[v];
        if (u == k || v == k) gd += TAU;
    }
    // Ms[rt][k][m]: rt<3 -> L0_s ; rt>=3 -> G_s.  g = rowsum(G)/2 -> gbuf
#pragma unroll
    for (int s = 0; s < 3; ++s) {
        float rs = 0.f;
#pragma unroll
        for (int o = 0; o < 16; ++o) rs += Wh[s][k][o];
        float l0 = (k == m) ? (rs + TAU) : -Wh[s][k][m];
        float G = gd + ((k == m) ? 4.f * Ts[s * 16 + k] : 0.f);
        Ms[s * 256 + tid] = l0;
        Ms[768 + s * 256 + tid] = G;
        float gg = G;
        for (int off = 8; off; off >>= 1) gg += __shfl_down(gg, off, 16);
        if (m == 0) gbuf[b * 48 + k * 3 + s] = 0.5f * gg;
    }
    __syncthreads();

    // Mcat rows: thread handles 2 adjacent q for 3 rt's (pair-packed stores)
    {
        const int q2 = (tid & 127) * 2;
        const int rtbase = (tid >> 7) * 3;
        float xv0[16], xv1[16];
#pragma unroll
        for (int l = 0; l < 16; ++l) { xv0[l] = XS[l][q2]; xv1[l] = XS[l][q2 + 1]; }
        const size_t obase = (size_t)b * 16 * 1536;
#pragma unroll
        for (int rtt = 0; rtt < 3; ++rtt) {
            const int rt = rtbase + rtt;
#pragma unroll
            for (int kk = 0; kk < 16; ++kk) {
                const float4* mp = (const float4*)&Ms[rt * 256 + kk * 16];
                float4 m0 = mp[0], m1 = mp[1], m2 = mp[2], m3 = mp[3];
                float a0 = m0.x * xv0[0] + m0.y * xv0[1] + m0.z * xv0[2] + m0.w * xv0[3]
                         + m1.x * xv0[4] + m1.y * xv0[5] + m1.z * xv0[6] + m1.w * xv0[7]
                         + m2.x * xv0[8] + m2.y * xv0[9] + m2.z * xv0[10] + m2.w * xv0[11]
                         + m3.x * xv0[12] + m3.y * xv0[13] + m3.z * xv0[14] + m3.w * xv0[15];
                float a1 = m0.x * xv1[0] + m0.y * xv1[1] + m0.z * xv1[2] + m0.w * xv1[3]
                         + m1.x * xv1[4] + m1.y * xv1[5] + m1.z * xv1[6] + m1.w * xv1[7]
                         + m2.x * xv1[8] + m2.y * xv1[9] + m2.z * xv1[10] + m2.w * xv1[11]
                         + m3.x * xv1[12] + m3.y * xv1[13] + m3.z * xv1[14] + m3.w * xv1[15];
                uint_t pk = (uint_t)f2bf(a0) | ((uint_t)f2bf(a1) << 16);
                *(uint_t*)&Mcat[obase + (size_t)kk * 1536 + rt * 256 + q2] = pk;
            }
        }
    }
}

// ---------------------------------------------------------------------------
// gemm cores (round-5 proven)
// ---------------------------------------------------------------------------
__device__ __forceinline__ void gemm128(const ushort_t* __restrict__ A,
                                        const ushort_t* __restrict__ Bt,
                                        int Kdim, int m0, int n0,
                                        f32x4 acc[4][4],
                                        ushort_t (*As)[32], ushort_t (*Bs)[32]) {
    const int tid = threadIdx.x;
    const int wave = tid >> 6, lane = tid & 63;
    const int lq = lane >> 4, lr = lane & 15;
    const int wm = wave >> 1, wn = wave & 1;
    const int r = tid >> 2, ca = (tid & 3) << 3;
    const ushort_t* Ag0 = A + (size_t)(m0 + r) * Kdim + ca;
    const ushort_t* Ag1 = A + (size_t)(m0 + 64 + r) * Kdim + ca;
    const ushort_t* Bg0 = Bt + (size_t)(n0 + r) * Kdim + ca;
    const ushort_t* Bg1 = Bt + (size_t)(n0 + 64 + r) * Kdim + ca;
    char* AsD0 = (char*)As + wave * 1024;
    char* AsD1 = (char*)As + 4096 + wave * 1024;
    char* BsD0 = (char*)Bs + wave * 1024;
    char* BsD1 = (char*)Bs + 4096 + wave * 1024;
    for (int kt = 0; kt < Kdim; kt += 32) {
        __syncthreads();
        glds16(Ag0 + kt, AsD0);
        glds16(Ag1 + kt, AsD1);
        glds16(Bg0 + kt, BsD0);
        glds16(Bg1 + kt, BsD1);
        __syncthreads();
        short8 af[4], bfr[4];
#pragma unroll
        for (int i = 0; i < 4; ++i) af[i] = *(const short8*)&As[wm * 64 + i * 16 + lr][lq * 8];
#pragma unroll
        for (int j = 0; j < 4; ++j) bfr[j] = *(const short8*)&Bs[wn * 64 + j * 16 + lr][lq * 8];
#pragma unroll
        for (int i = 0; i < 4; ++i)
#pragma unroll
            for (int j = 0; j < 4; ++j)
                acc[i][j] = __builtin_amdgcn_mfma_f32_16x16x32_bf16(af[i], bfr[j], acc[i][j], 0, 0, 0);
    }
}

__device__ __forceinline__ void gemm64(const ushort_t* __restrict__ A,
                                       const ushort_t* __restrict__ Bt,
                                       int Kdim, int m0, int n0,
                                       f32x4 acc[2][4],
                                       ushort_t (*As)[32], ushort_t (*Bs)[32]) {
    const int tid = threadIdx.x;
    const int wave = tid >> 6, lane = tid & 63;
    const int lq = lane >> 4, lr = lane & 15;
    const int wm = wave >> 1, wn = wave & 1;
    const int r = tid >> 2, ca = (tid & 3) << 3;
    const ushort_t* Ag = A + (size_t)(m0 + r) * Kdim + ca;
    const ushort_t* Bg0 = Bt + (size_t)(n0 + r) * Kdim + ca;
    const ushort_t* Bg1 = Bt + (size_t)(n0 + 64 + r) * Kdim + ca;
    char* AsD = (char*)As + wave * 1024;
    char* Bs0D = (char*)Bs + wave * 1024;
    char* Bs1D = (char*)Bs + 4096 + wave * 1024;
    for (int kt = 0; kt < Kdim; kt += 32) {
        __syncthreads();
        glds16(Ag + kt, AsD);
        glds16(Bg0 + kt, Bs0D);
        glds16(Bg1 + kt, Bs1D);
        __syncthreads();
        short8 af[2], bfr[4];
#pragma unroll
        for (int i = 0; i < 2; ++i) af[i] = *(const short8*)&As[wm * 32 + i * 16 + lr][lq * 8];
#pragma unroll
        for (int j = 0; j < 4; ++j) bfr[j] = *(const short8*)&Bs[wn * 64 + j * 16 + lr][lq * 8];
#pragma unroll
        for (int i = 0; i < 2; ++i)
#pragma unroll
            for (int j = 0; j < 4; ++j)
                acc[i][j] = __builtin_amdgcn_mfma_f32_16x16x32_bf16(af[i], bfr[j], acc[i][j], 0, 0, 0);
    }
}

// kZY: xp = Mcat @ Wcat + x + cv + sum_s g_s*beWo_s. M=16384,N=256,K=1536.
// 64x128 tiles, grid (256,2) = 512 blocks.
__global__ __launch_bounds__(256) void kZY_gemm(
    const ushort_t* __restrict__ Mcat, const ushort_t* __restrict__ WcatT,
    const float* __restrict__ xin, const float* __restrict__ bo,
    const float* __restrict__ cvpart, const float* __restrict__ beWo,
    const float* __restrict__ gbuf, float* __restrict__ xp) {
    __shared__ ushort_t As[64][32];
    __shared__ ushort_t Bs[128][32];
    __shared__ float cvS[128], bewS[3][128], gblk[64][3];
    const int tid = threadIdx.x;
    const int m0 = blockIdx.x * 64, n0 = blockIdx.y * 128;
    if (tid < 128) {
        int n = n0 + tid;
        cvS[tid] = bo[n] + TAU * (cvpart[n] + cvpart[256 + n] + cvpart[512 + n]);
        bewS[0][tid] = beWo[n];
        bewS[1][tid] = beWo[256 + n];
        bewS[2][tid] = beWo[512 + n];
    }
    if (tid < 192) { int rr = tid / 3, s = tid - rr * 3; gblk[rr][s] = gbuf[(size_t)(m0 + rr) * 3 + s]; }
    f32x4 acc[2][4] = {};
    gemm64(Mcat, WcatT, 1536, m0, n0, acc, As, Bs);
    const int wave = tid >> 6, lane = tid & 63, lq = lane >> 4, lr = lane & 15;
    const int wm = wave >> 1, wn = wave & 1;
#pragma unroll
    for (int i = 0; i < 2; ++i)
#pragma unroll
        for (int j = 0; j < 4; ++j) {
            int nl = wn * 64 + j * 16 + lr;
#pragma unroll
            for (int v = 0; v < 4; ++v) {
                int rl = wm * 32 + i * 16 + lq * 4 + v;
                size_t idx = (size_t)(m0 + rl) * 256 + n0 + nl;
                xp[idx] = acc[i][j][v] + xin[idx] + cvS[nl] +
                          gblk[rl][0] * bewS[0][nl] + gblk[rl][1] * bewS[1][nl] +
                          gblk[rl][2] * bewS[2][nl];
            }
        }
}

// LN2 -> h (bf16). grid 4096, 4 rows/block.
__global__ __launch_bounds__(256) void k_ln2(const float* __restrict__ xp,
                                             const float* __restrict__ g2,
                                             const float* __restrict__ b2,
                                             ushort_t* __restrict__ h) {
    const int tid = threadIdx.x;
    const int row = blockIdx.x * 4 + (tid >> 6);
    const int lane = tid & 63;
    const float* xr = xp + (size_t)row * 256;
    float v0 = xr[lane], v1 = xr[lane + 64], v2 = xr[lane + 128], v3 = xr[lane + 192];
    float s = v0 + v1 + v2 + v3;
    for (int m = 32; m; m >>= 1) s += __shfl_xor(s, m, 64);
    float mean = s * (1.f / 256.f);
    float d0 = v0 - mean, d1 = v1 - mean, d2 = v2 - mean, d3 = v3 - mean;
    float q = d0 * d0 + d1 * d1 + d2 * d2 + d3 * d3;
    for (int m = 32; m; m >>= 1) q += __shfl_xor(q, m, 64);
    float rstd = rsqrtf(q * (1.f / 256.f) + LN_EPS);
    ushort_t* hr = h + (size_t)row * 256;
    hr[lane] = f2bf(d0 * rstd * g2[lane] + b2[lane]);
    hr[lane + 64] = f2bf(d1 * rstd * g2[lane + 64] + b2[lane + 64]);
    hr[lane + 128] = f2bf(d2 * rstd * g2[lane + 128] + b2[lane + 128]);
    hr[lane + 192] = f2bf(d3 * rstd * g2[lane + 192] + b2[lane + 192]);
}

// K3: F1g = gelu(h @ Wf1 + bf1), 128x128, grid (128,8)
__global__ __launch_bounds__(256) void k3_gemm(const ushort_t* __restrict__ h,
                                               const ushort_t* __restrict__ Wf1T,
                                               const float* __restrict__ bf1,
                                               ushort_t* __restrict__ F1g) {
    __shared__ ushort_t As[128][32];
    __shared__ ushort_t Bs[128][32];
    const int tid = threadIdx.x;
    const int m0 = blockIdx.x * 128, n0 = blockIdx.y * 128;
    f32x4 acc[4][4] = {};
    gemm128(h, Wf1T, 256, m0, n0, acc, As, Bs);
    const int wave = tid >> 6, lane = tid & 63, lq = lane >> 4, lr = lane & 15;
    const int wm = wave >> 1, wn = wave & 1;
#pragma unroll
    for (int i = 0; i < 4; ++i)
#pragma unroll
        for (int j = 0; j < 4; ++j) {
            int n = n0 + wn * 64 + j * 16 + lr;
            float bn = bf1[n];
#pragma unroll
            for (int v = 0; v < 4; ++v) {
                int rg = m0 + wm * 64 + i * 16 + lq * 4 + v;
                float u = acc[i][j][v] + bn;
                float gl = 0.5f * u * (1.f + erff(u * 0.70710678118f));
                F1g[(size_t)rg * 1024 + n] = f2bf(gl);
            }
        }
}

// K4: out = xp + F1g @ Wf2 + bf2, 64x128, grid (256,2)
__global__ __launch_bounds__(256) void k4_gemm(const ushort_t* __restrict__ F1g,
                                               const ushort_t* __restrict__ Wf2T,
                                               const float* __restrict__ bf2,
                                               const float* __restrict__ xp,
                                               float* __restrict__ out) {
    __shared__ ushort_t As[64][32];
    __shared__ ushort_t Bs[128][32];
    const int tid = threadIdx.x;
    const int m0 = blockIdx.x * 64, n0 = blockIdx.y * 128;
    f32x4 acc[2][4] = {};
    gemm64(F1g, Wf2T, 1024, m0, n0, acc, As, Bs);
    const int wave = tid >> 6, lane = tid & 63, lq = lane >> 4, lr = lane & 15;
    const int wm = wave >> 1, wn = wave & 1;
#pragma unroll
    for (int i = 0; i < 2; ++i)
#pragma unroll
        for (int j = 0; j < 4; ++j) {
            int n = n0 + wn * 64 + j * 16 + lr;
            float bn = bf2[n];
#pragma unroll
            for (int v = 0; v < 4; ++v) {
                size_t idx = (size_t)(m0 + wm * 32 + i * 16 + lq * 4 + v) * 256 + n;
                out[idx] = xp[idx] + acc[i][j][v] + bn;
            }
        }
}

extern "C" void kernel_launch(void* const* d_in, const int* in_sizes, int n_in,
                              void* d_out, int out_size, void* d_ws, size_t ws_size,
                              hipStream_t stream) {
    const float* x = (const float*)d_in[0];
    const float* mask = (const float*)d_in[1];
    const float* Wg = (const float*)d_in[2];
    const float* bg = (const float*)d_in[3];
    const float* ls = (const float*)d_in[4];
    const float* Wv = (const float*)d_in[5];
    const float* bv = (const float*)d_in[6];
    const float* We = (const float*)d_in[7];
    const float* be = (const float*)d_in[8];
    const float* Wo = (const float*)d_in[9];
    const float* bo = (const float*)d_in[10];
    const float* g1 = (const float*)d_in[11];
    const float* b1 = (const float*)d_in[12];
    const float* g2 = (const float*)d_in[13];
    const float* b2 = (const float*)d_in[14];
    const float* Wf1 = (const float*)d_in[15];
    const float* bf1 = (const float*)d_in[16];
    const float* Wf2 = (const float*)d_in[17];
    const float* bf2 = (const float*)d_in[18];
    float* out = (float*)d_out;

    char* ws = (char*)d_ws;
    ushort_t* Mcat = (ushort_t*)(ws);                   // 50,331,648
    ushort_t* F1g = (ushort_t*)(ws);                    // 33,554,432 (alias: Mcat dead after kZY)
    ushort_t* WcatT = (ushort_t*)(ws + 50331648);       //    786,432
    ushort_t* Wf1T = (ushort_t*)(ws + 51118080);        //    524,288
    ushort_t* Wf2T = (ushort_t*)(ws + 51642368);        //    524,288
    float* cvpart = (float*)(ws + 52166656);            //      3,072
    float* beWo = (float*)(ws + 52169728);              //      3,072
    float* gbuf = (float*)(ws + 52172800);              //    196,608
    float* xp = (float*)(ws + 52369408);                // 16,777,216
    ushort_t* h = (ushort_t*)(ws + 69146624);           //  8,388,608  -> end 77,535,232

    kA<<<dim3(1542), dim3(256), 0, stream>>>(x, mask, Wg, bg, ls, g1, b1,
                                             Mcat, gbuf,
                                             Wv, We, Wo, bv, be, Wf1, Wf2,
                                             WcatT, Wf1T, Wf2T, cvpart, beWo);
    kZY_gemm<<<dim3(256, 2), dim3(256), 0, stream>>>(Mcat, WcatT, x, bo, cvpart, beWo, gbuf, xp);
    k_ln2<<<dim3(4096), dim3(256), 0, stream>>>(xp, g2, b2, h);
    k3_gemm<<<dim3(128, 8), dim3(256), 0, stream>>>(h, Wf1T, bf1, F1g);
    k4_gemm<<<dim3(256, 2), dim3(256), 0, stream>>>(F1g, Wf2T, bf2, xp, out);
}